// Round 4
// baseline (218.845 us; speedup 1.0000x reference)
//
#include <hip/hip_runtime.h>

// Problem constants
constexpr int S = 7, NB = 2, C = 20, E = 30;      // E = NB*5 + C = 30
constexpr int BATCH = 16384;
constexpr int NCELLS = BATCH * S * S;             // 802816

__global__ void zero_out_kernel(float* out) {
    if (threadIdx.x < 5) out[threadIdx.x] = 0.0f;
}

// Direct-load version, scratch-spill-free.
// Each thread owns one cell (30 contiguous floats = 120 B); a wave's 15
// float2 loads fully consume every cache line in its 7680 B span.
// CRITICAL (round-2 post-mortem): no runtime indexing into p[]/t[] --
// runtime-indexed arrays are demoted to scratch (was: VGPR=44, 27 MB of
// scratch writes/iter, dur 81us). The responsible-box choice is done with
// explicit compile-time-indexed selects instead.
__global__ __launch_bounds__(256, 4) void yolo_loss_kernel(
    const float* __restrict__ pred,
    const float* __restrict__ tgt,
    float* __restrict__ out)
{
    const int tid      = blockIdx.x * blockDim.x + threadIdx.x;
    const int nthreads = gridDim.x * blockDim.x;
    const int lane     = threadIdx.x & 63;
    const int wv       = threadIdx.x >> 6;

    float acc0 = 0.f, acc1 = 0.f, acc2 = 0.f, acc3 = 0.f, acc4 = 0.f;

    for (int cell = tid; cell < NCELLS; cell += nthreads) {
        const float2* gp = reinterpret_cast<const float2*>(pred) + (size_t)cell * 15;
        const float2* gt = reinterpret_cast<const float2*>(tgt)  + (size_t)cell * 15;

        // 30 independent loads; all array indices below are compile-time
        // constants so p[]/t[] live entirely in VGPRs.
        float p[30], t[30];
        #pragma unroll
        for (int j = 0; j < 15; ++j) {
            float2 a = gp[j]; p[2*j] = a.x; p[2*j+1] = a.y;
        }
        #pragma unroll
        for (int j = 0; j < 15; ++j) {
            float2 b = gt[j]; t[2*j] = b.x; t[2*j+1] = b.y;
        }

        const float tconf = t[4];                 // exactly 0.0 or 1.0
        const float m  = (tconf > 0.0f)  ? 1.0f : 0.0f;
        const float nm = 1.0f - m;

        // IoU of each pred box vs target box 0 (channels 0..3)
        const float t0x1 = t[0], t0y1 = t[1], t0x2 = t[2], t0y2 = t[3];
        const float a2 = (t0x2 - t0x1) * (t0y2 - t0y1);

        float iou0, iou1;
        {
            const float ltx = fmaxf(p[0], t0x1), lty = fmaxf(p[1], t0y1);
            const float rbx = fminf(p[2], t0x2), rby = fminf(p[3], t0y2);
            const float wx = fmaxf(rbx - ltx, 0.0f), wy = fmaxf(rby - lty, 0.0f);
            const float inter = wx * wy;
            const float a1 = (p[2] - p[0]) * (p[3] - p[1]);
            iou0 = inter / (a1 + a2 - inter);
        }
        {
            const float ltx = fmaxf(p[5], t0x1), lty = fmaxf(p[6], t0y1);
            const float rbx = fminf(p[7], t0x2), rby = fminf(p[8], t0y2);
            const float wx = fmaxf(rbx - ltx, 0.0f), wy = fmaxf(rby - lty, 0.0f);
            const float inter = wx * wy;
            const float a1 = (p[7] - p[5]) * (p[8] - p[6]);
            iou1 = inter / (a1 + a2 - inter);
        }

        const float max_iou = fmaxf(iou0, iou1);
        // argmax, first index wins ties: box1 responsible iff iou1 > iou0
        const bool b1 = iou1 > iou0;

        // Explicit selects (v_cndmask) -- compile-time indices only.
        const float rpx = b1 ? p[5] : p[0];
        const float rpy = b1 ? p[6] : p[1];
        const float rpw = b1 ? p[7] : p[2];
        const float rph = b1 ? p[8] : p[3];
        const float rpc = b1 ? p[9] : p[4];
        const float rtx = b1 ? t[5] : t[0];
        const float rty = b1 ? t[6] : t[1];
        const float rtw = b1 ? t[7] : t[2];
        const float rth = b1 ? t[8] : t[3];

        {   // xy
            const float dx = rpx - rtx;
            const float dy = rpy - rty;
            acc0 += m * (dx*dx + dy*dy);
        }
        {   // wh (sqrt space; inputs in (0.05, 0.95) so sqrt args > 0)
            const float dw = sqrtf(rpw) - sqrtf(rtw);
            const float dh = sqrtf(rph) - sqrtf(rth);
            acc1 += m * (dw*dw + dh*dh);
        }
        {   // obj
            const float d = rpc - max_iou;
            acc2 += m * d * d;
        }
        {   // noobj (channels 4, 9)
            const float d0 = p[4] - t[4];
            const float d1 = p[9] - t[9];
            acc3 += nm * (d0*d0 + d1*d1);
        }
        {   // class (channels 10..29)
            float cl = 0.f;
            #pragma unroll
            for (int k = 10; k < 30; ++k) {
                const float d = p[k] - t[k];
                cl += d * d;
            }
            acc4 += m * cl;
        }
    }

    // ---- reduction: wave (64) -> block -> global atomics ----
    float acc[5] = {acc0, acc1, acc2, acc3, acc4};
    __shared__ float wave_sums[4][5];
    #pragma unroll
    for (int i = 0; i < 5; ++i) {
        float v = acc[i];
        #pragma unroll
        for (int o = 32; o > 0; o >>= 1)
            v += __shfl_down(v, o, 64);
        if (lane == 0) wave_sums[wv][i] = v;
    }
    __syncthreads();

    if (threadIdx.x < 5) {
        const float v = wave_sums[0][threadIdx.x] + wave_sums[1][threadIdx.x]
                      + wave_sums[2][threadIdx.x] + wave_sums[3][threadIdx.x];
        atomicAdd(out + threadIdx.x, v);
    }
}

extern "C" void kernel_launch(void* const* d_in, const int* in_sizes, int n_in,
                              void* d_out, int out_size, void* d_ws, size_t ws_size,
                              hipStream_t stream) {
    const float* pred = (const float*)d_in[0];
    const float* tgt  = (const float*)d_in[1];
    float* out = (float*)d_out;

    hipLaunchKernelGGL(zero_out_kernel, dim3(1), dim3(64), 0, stream, out);

    // 1024 blocks x 256 threads = 4096 waves = 16 waves/CU resident.
    // Each thread handles 3-4 cells via grid-stride.
    hipLaunchKernelGGL(yolo_loss_kernel, dim3(1024), dim3(256), 0, stream,
                       pred, tgt, out);
}

// Round 7
// 213.892 us; speedup vs baseline: 1.0232x; 1.0232x over previous
//
#include <hip/hip_runtime.h>

// Problem constants
constexpr int S = 7, NB = 2, C = 20, E = 30;      // E = NB*5 + C = 30
constexpr int BATCH = 16384;
constexpr int NCELLS = BATCH * S * S;             // 802816
constexpr int NPAIRS = NCELLS / 2;                // 401408

__global__ void zero_out_kernel(float* out) {
    if (threadIdx.x < 5) out[threadIdx.x] = 0.0f;
}

// Pair-of-cells version. Round-4 post-mortem: limiter is the memory request
// path -- lane stride 120 B means every wave-load touches 64 distinct lines,
// and each 64 B line is requested ~8x via separate float2 loads (24 M line
// requests ~= 19 TB/s of L2 request traffic; VALUBusy 6%, HBM 26%).
// Fix: one thread owns TWO adjacent cells = 240 B = exactly 15 x 16 B, so
// all loads are aligned dwordx4 -> 15 requests/cell instead of 30, zero
// line-crossing. All indices compile-time (round-2 lesson: runtime indexing
// demotes arrays to scratch).
__global__ __launch_bounds__(256) void yolo_loss_kernel(
    const float* __restrict__ pred,
    const float* __restrict__ tgt,
    float* __restrict__ out)
{
    const int pair = blockIdx.x * blockDim.x + threadIdx.x;
    const int lane = threadIdx.x & 63;
    const int wv   = threadIdx.x >> 6;

    float acc0 = 0.f, acc1 = 0.f, acc2 = 0.f, acc3 = 0.f, acc4 = 0.f;

    if (pair < NPAIRS) {
        const float4* gp = reinterpret_cast<const float4*>(pred + (size_t)pair * 60);
        const float4* gt = reinterpret_cast<const float4*>(tgt  + (size_t)pair * 60);

        // 30 aligned dwordx4 loads; indices all compile-time constants.
        float p[60], t[60];
        #pragma unroll
        for (int j = 0; j < 15; ++j) {
            float4 a = gp[j];
            p[4*j+0] = a.x; p[4*j+1] = a.y; p[4*j+2] = a.z; p[4*j+3] = a.w;
        }
        #pragma unroll
        for (int j = 0; j < 15; ++j) {
            float4 b = gt[j];
            t[4*j+0] = b.x; t[4*j+1] = b.y; t[4*j+2] = b.z; t[4*j+3] = b.w;
        }

        // Per-cell loss, OFF is a literal (0 or 30) so all indices fold.
        #define CELL_LOSS(OFF)                                                     \
        {                                                                          \
            const float tconf = t[(OFF)+4];              /* exactly 0.0 or 1.0 */  \
            const float m  = (tconf > 0.0f) ? 1.0f : 0.0f;                         \
            const float nm = 1.0f - m;                                             \
            const float t0x1 = t[(OFF)+0], t0y1 = t[(OFF)+1];                      \
            const float t0x2 = t[(OFF)+2], t0y2 = t[(OFF)+3];                      \
            const float a2 = (t0x2 - t0x1) * (t0y2 - t0y1);                        \
            float iou0, iou1;                                                      \
            {                                                                      \
                const float ltx = fmaxf(p[(OFF)+0], t0x1);                         \
                const float lty = fmaxf(p[(OFF)+1], t0y1);                         \
                const float rbx = fminf(p[(OFF)+2], t0x2);                         \
                const float rby = fminf(p[(OFF)+3], t0y2);                         \
                const float wx = fmaxf(rbx - ltx, 0.0f);                           \
                const float wy = fmaxf(rby - lty, 0.0f);                           \
                const float inter = wx * wy;                                       \
                const float a1 = (p[(OFF)+2] - p[(OFF)+0])                         \
                               * (p[(OFF)+3] - p[(OFF)+1]);                        \
                iou0 = inter / (a1 + a2 - inter);                                  \
            }                                                                      \
            {                                                                      \
                const float ltx = fmaxf(p[(OFF)+5], t0x1);                         \
                const float lty = fmaxf(p[(OFF)+6], t0y1);                         \
                const float rbx = fminf(p[(OFF)+7], t0x2);                         \
                const float rby = fminf(p[(OFF)+8], t0y2);                         \
                const float wx = fmaxf(rbx - ltx, 0.0f);                           \
                const float wy = fmaxf(rby - lty, 0.0f);                           \
                const float inter = wx * wy;                                       \
                const float a1 = (p[(OFF)+7] - p[(OFF)+5])                         \
                               * (p[(OFF)+8] - p[(OFF)+6]);                        \
                iou1 = inter / (a1 + a2 - inter);                                  \
            }                                                                      \
            const float max_iou = fmaxf(iou0, iou1);                               \
            const bool b1 = iou1 > iou0;       /* first index wins ties */         \
            const float rpx = b1 ? p[(OFF)+5] : p[(OFF)+0];                        \
            const float rpy = b1 ? p[(OFF)+6] : p[(OFF)+1];                        \
            const float rpw = b1 ? p[(OFF)+7] : p[(OFF)+2];                        \
            const float rph = b1 ? p[(OFF)+8] : p[(OFF)+3];                        \
            const float rpc = b1 ? p[(OFF)+9] : p[(OFF)+4];                        \
            const float rtx = b1 ? t[(OFF)+5] : t[(OFF)+0];                        \
            const float rty = b1 ? t[(OFF)+6] : t[(OFF)+1];                        \
            const float rtw = b1 ? t[(OFF)+7] : t[(OFF)+2];                        \
            const float rth = b1 ? t[(OFF)+8] : t[(OFF)+3];                        \
            {   /* xy */                                                           \
                const float dx = rpx - rtx;                                        \
                const float dy = rpy - rty;                                        \
                acc0 += m * (dx*dx + dy*dy);                                       \
            }                                                                      \
            {   /* wh: inputs in (0.05,0.95) so sqrt args > 0 */                   \
                const float dw = sqrtf(rpw) - sqrtf(rtw);                          \
                const float dh = sqrtf(rph) - sqrtf(rth);                          \
                acc1 += m * (dw*dw + dh*dh);                                       \
            }                                                                      \
            {   /* obj */                                                          \
                const float d = rpc - max_iou;                                     \
                acc2 += m * d * d;                                                 \
            }                                                                      \
            {   /* noobj: channels 4, 9 */                                         \
                const float d0 = p[(OFF)+4] - t[(OFF)+4];                          \
                const float d1 = p[(OFF)+9] - t[(OFF)+9];                          \
                acc3 += nm * (d0*d0 + d1*d1);                                      \
            }                                                                      \
            {   /* class: channels 10..29 */                                       \
                float cl = 0.f;                                                    \
                _Pragma("unroll")                                                  \
                for (int k = 10; k < 30; ++k) {                                    \
                    const float d = p[(OFF)+k] - t[(OFF)+k];                       \
                    cl += d * d;                                                   \
                }                                                                  \
                acc4 += m * cl;                                                    \
            }                                                                      \
        }

        CELL_LOSS(0)
        CELL_LOSS(30)
        #undef CELL_LOSS
    }

    // ---- reduction: wave (64) -> block -> global atomics ----
    float acc[5] = {acc0, acc1, acc2, acc3, acc4};
    __shared__ float wave_sums[4][5];
    #pragma unroll
    for (int i = 0; i < 5; ++i) {
        float v = acc[i];
        #pragma unroll
        for (int o = 32; o > 0; o >>= 1)
            v += __shfl_down(v, o, 64);
        if (lane == 0) wave_sums[wv][i] = v;
    }
    __syncthreads();

    if (threadIdx.x < 5) {
        const float v = wave_sums[0][threadIdx.x] + wave_sums[1][threadIdx.x]
                      + wave_sums[2][threadIdx.x] + wave_sums[3][threadIdx.x];
        atomicAdd(out + threadIdx.x, v);
    }
}

extern "C" void kernel_launch(void* const* d_in, const int* in_sizes, int n_in,
                              void* d_out, int out_size, void* d_ws, size_t ws_size,
                              hipStream_t stream) {
    const float* pred = (const float*)d_in[0];
    const float* tgt  = (const float*)d_in[1];
    float* out = (float*)d_out;

    hipLaunchKernelGGL(zero_out_kernel, dim3(1), dim3(64), 0, stream, out);

    // 1568 blocks x 256 threads = 401408 threads = exactly one cell-pair each.
    hipLaunchKernelGGL(yolo_loss_kernel, dim3(1568), dim3(256), 0, stream,
                       pred, tgt, out);
}

// Round 12
// 213.574 us; speedup vs baseline: 1.0247x; 1.0015x over previous
//
#include <hip/hip_runtime.h>

// Problem constants
constexpr int S = 7, NB = 2, C = 20, E = 30;      // E = NB*5 + C = 30
constexpr int BATCH = 16384;
constexpr int NCELLS = BATCH * S * S;             // 802816
constexpr int NPAIRS = NCELLS / 2;                // 401408

__global__ void zero_out_kernel(float* out) {
    if (threadIdx.x < 5) out[threadIdx.x] = 0.0f;
}

// Pair-of-cells dwordx4 version, VGPR-unthrottled.
// Round-7 post-mortem: at the default launch bounds the compiler capped the
// kernel at 64 VGPRs (default assumes 1024-thread blocks), far below the
// ~120 needed to hold p[60]+t[60] live. It therefore SANK loads into uses
// -> ~15 serialized global_load->vmcnt batches per thread -> ~3 KB in
// flight per CU (Little's law at 2 TB/s), latency-serialized at 6% VALU /
// 26% HBM. Request-count changes (r4->r7) were neutral because
// serialization, not request count, was the limiter.
// Fix: __launch_bounds__(256, 1) lifts the VGPR cap to 512 so all 30
// dwordx4 loads issue back-to-back with ONE vmcnt wait. 3 waves/SIMD with
// 30 outstanding 1KB loads each ~= 360 KB/CU in flight >> the ~9 KB needed
// for full HBM bandwidth.
__global__ __launch_bounds__(256, 1) void yolo_loss_kernel(
    const float* __restrict__ pred,
    const float* __restrict__ tgt,
    float* __restrict__ out)
{
    const int pair = blockIdx.x * blockDim.x + threadIdx.x;
    const int lane = threadIdx.x & 63;
    const int wv   = threadIdx.x >> 6;

    float acc0 = 0.f, acc1 = 0.f, acc2 = 0.f, acc3 = 0.f, acc4 = 0.f;

    if (pair < NPAIRS) {
        const float4* gp = reinterpret_cast<const float4*>(pred + (size_t)pair * 60);
        const float4* gt = reinterpret_cast<const float4*>(tgt  + (size_t)pair * 60);

        // 30 aligned dwordx4 loads; indices all compile-time constants so
        // p[]/t[] live entirely in VGPRs (round-2 lesson: no runtime indexing).
        float p[60], t[60];
        #pragma unroll
        for (int j = 0; j < 15; ++j) {
            float4 a = gp[j];
            p[4*j+0] = a.x; p[4*j+1] = a.y; p[4*j+2] = a.z; p[4*j+3] = a.w;
        }
        #pragma unroll
        for (int j = 0; j < 15; ++j) {
            float4 b = gt[j];
            t[4*j+0] = b.x; t[4*j+1] = b.y; t[4*j+2] = b.z; t[4*j+3] = b.w;
        }

        // Per-cell loss, OFF is a literal (0 or 30) so all indices fold.
        #define CELL_LOSS(OFF)                                                     \
        {                                                                          \
            const float tconf = t[(OFF)+4];              /* exactly 0.0 or 1.0 */  \
            const float m  = (tconf > 0.0f) ? 1.0f : 0.0f;                         \
            const float nm = 1.0f - m;                                             \
            const float t0x1 = t[(OFF)+0], t0y1 = t[(OFF)+1];                      \
            const float t0x2 = t[(OFF)+2], t0y2 = t[(OFF)+3];                      \
            const float a2 = (t0x2 - t0x1) * (t0y2 - t0y1);                        \
            float iou0, iou1;                                                      \
            {                                                                      \
                const float ltx = fmaxf(p[(OFF)+0], t0x1);                         \
                const float lty = fmaxf(p[(OFF)+1], t0y1);                         \
                const float rbx = fminf(p[(OFF)+2], t0x2);                         \
                const float rby = fminf(p[(OFF)+3], t0y2);                         \
                const float wx = fmaxf(rbx - ltx, 0.0f);                           \
                const float wy = fmaxf(rby - lty, 0.0f);                           \
                const float inter = wx * wy;                                       \
                const float a1 = (p[(OFF)+2] - p[(OFF)+0])                         \
                               * (p[(OFF)+3] - p[(OFF)+1]);                        \
                iou0 = inter / (a1 + a2 - inter);                                  \
            }                                                                      \
            {                                                                      \
                const float ltx = fmaxf(p[(OFF)+5], t0x1);                         \
                const float lty = fmaxf(p[(OFF)+6], t0y1);                         \
                const float rbx = fminf(p[(OFF)+7], t0x2);                         \
                const float rby = fminf(p[(OFF)+8], t0y2);                         \
                const float wx = fmaxf(rbx - ltx, 0.0f);                           \
                const float wy = fmaxf(rby - lty, 0.0f);                           \
                const float inter = wx * wy;                                       \
                const float a1 = (p[(OFF)+7] - p[(OFF)+5])                         \
                               * (p[(OFF)+8] - p[(OFF)+6]);                        \
                iou1 = inter / (a1 + a2 - inter);                                  \
            }                                                                      \
            const float max_iou = fmaxf(iou0, iou1);                               \
            const bool b1 = iou1 > iou0;       /* first index wins ties */         \
            const float rpx = b1 ? p[(OFF)+5] : p[(OFF)+0];                        \
            const float rpy = b1 ? p[(OFF)+6] : p[(OFF)+1];                        \
            const float rpw = b1 ? p[(OFF)+7] : p[(OFF)+2];                        \
            const float rph = b1 ? p[(OFF)+8] : p[(OFF)+3];                        \
            const float rpc = b1 ? p[(OFF)+9] : p[(OFF)+4];                        \
            const float rtx = b1 ? t[(OFF)+5] : t[(OFF)+0];                        \
            const float rty = b1 ? t[(OFF)+6] : t[(OFF)+1];                        \
            const float rtw = b1 ? t[(OFF)+7] : t[(OFF)+2];                        \
            const float rth = b1 ? t[(OFF)+8] : t[(OFF)+3];                        \
            {   /* xy */                                                           \
                const float dx = rpx - rtx;                                        \
                const float dy = rpy - rty;                                        \
                acc0 += m * (dx*dx + dy*dy);                                       \
            }                                                                      \
            {   /* wh: inputs in (0.05,0.95) so sqrt args > 0 */                   \
                const float dw = sqrtf(rpw) - sqrtf(rtw);                          \
                const float dh = sqrtf(rph) - sqrtf(rth);                          \
                acc1 += m * (dw*dw + dh*dh);                                       \
            }                                                                      \
            {   /* obj */                                                          \
                const float d = rpc - max_iou;                                     \
                acc2 += m * d * d;                                                 \
            }                                                                      \
            {   /* noobj: channels 4, 9 */                                         \
                const float d0 = p[(OFF)+4] - t[(OFF)+4];                          \
                const float d1 = p[(OFF)+9] - t[(OFF)+9];                          \
                acc3 += nm * (d0*d0 + d1*d1);                                      \
            }                                                                      \
            {   /* class: channels 10..29 */                                       \
                float cl = 0.f;                                                    \
                _Pragma("unroll")                                                  \
                for (int k = 10; k < 30; ++k) {                                    \
                    const float d = p[(OFF)+k] - t[(OFF)+k];                       \
                    cl += d * d;                                                   \
                }                                                                  \
                acc4 += m * cl;                                                    \
            }                                                                      \
        }

        CELL_LOSS(0)
        CELL_LOSS(30)
        #undef CELL_LOSS
    }

    // ---- reduction: wave (64) -> block -> global atomics ----
    float acc[5] = {acc0, acc1, acc2, acc3, acc4};
    __shared__ float wave_sums[4][5];
    #pragma unroll
    for (int i = 0; i < 5; ++i) {
        float v = acc[i];
        #pragma unroll
        for (int o = 32; o > 0; o >>= 1)
            v += __shfl_down(v, o, 64);
        if (lane == 0) wave_sums[wv][i] = v;
    }
    __syncthreads();

    if (threadIdx.x < 5) {
        const float v = wave_sums[0][threadIdx.x] + wave_sums[1][threadIdx.x]
                      + wave_sums[2][threadIdx.x] + wave_sums[3][threadIdx.x];
        atomicAdd(out + threadIdx.x, v);
    }
}

extern "C" void kernel_launch(void* const* d_in, const int* in_sizes, int n_in,
                              void* d_out, int out_size, void* d_ws, size_t ws_size,
                              hipStream_t stream) {
    const float* pred = (const float*)d_in[0];
    const float* tgt  = (const float*)d_in[1];
    float* out = (float*)d_out;

    hipLaunchKernelGGL(zero_out_kernel, dim3(1), dim3(64), 0, stream, out);

    // 1568 blocks x 256 threads = 401408 threads = exactly one cell-pair each.
    hipLaunchKernelGGL(yolo_loss_kernel, dim3(1568), dim3(256), 0, stream,
                       pred, tgt, out);
}